// Round 7
// baseline (917.404 us; speedup 1.0000x reference)
//
#include <hip/hip_runtime.h>

#define N0c 100000
#define N1c 25000
#define N2c 5000
#define E0c 400000
#define E1c 80000
// IN_FEATS = N_HIDDEN = 512, N_CLASSES = 64
// M-tiles (128 rows): GEMM1 782, GEMM2 196

typedef __attribute__((ext_vector_type(8))) short bf16x8;
typedef __attribute__((ext_vector_type(4))) float f32x4;

#define GLOAD_LDS(g, l) \
    __builtin_amdgcn_global_load_lds((__attribute__((address_space(1))) const unsigned int*)(const void*)(g), \
                                     (__attribute__((address_space(3))) unsigned int*)(void*)(l), 16, 0, 0)

// round-to-nearest-even bf16, returned as fp32 bit pattern (low 16 zeroed)
static __device__ __forceinline__ uint rnd_bf(float f) {
    uint u = __float_as_uint(f);
    return (u + 0x7FFFu + ((u >> 16) & 1u)) & 0xFFFF0000u;
}
static __device__ __forceinline__ unsigned short to_bf(float f) {
    return (unsigned short)(rnd_bf(f) >> 16);
}
// pack two floats -> one uint holding 2 bf16 (low = f0, high = f1)
static __device__ __forceinline__ uint pk_bf(float f0, float f1) {
    return (rnd_bf(f0) >> 16) | rnd_bf(f1);
}

// ---------------------------------------------------------------------------
// Pre-convert (weights only): X[512][512] fp32 -> bf16 tiled planes.
// Tile = 128 rows x 64 k = 16 KiB: [r=128][p=8 x 16B slots], physical slot
// p holds k-octet o = p ^ (r&7) (k = kt8*64 + o*8). Buffer [mt*8+kt8][1024].
// ---------------------------------------------------------------------------
__global__ __launch_bounds__(256)
void presplit_bf(const float* __restrict__ X, uint4* __restrict__ out,
                 int M, int tile0, int ntiles)
{
    const int id = blockIdx.x * 256 + threadIdx.x;
    const int slot = id & 1023;            // r*8 + p
    const int tk = id >> 10;               // mtl*8 + kt8
    if (tk >= ntiles * 8) return;
    const int kt8 = tk & 7, mtl = tk >> 3;
    const int r = slot >> 3, p = slot & 7;
    const int o = p ^ (r & 7);
    const int row = (tile0 + mtl) * 128 + r;
    uint4 v = {0u, 0u, 0u, 0u};
    if (row < M) {
        const float* src = X + (size_t)row * 512 + kt8 * 64 + o * 8;
        float4 x0 = *(const float4*)src;
        float4 x1 = *(const float4*)(src + 4);
        v.x = pk_bf(x0.x, x0.y); v.y = pk_bf(x0.z, x0.w);
        v.z = pk_bf(x1.x, x1.y); v.w = pk_bf(x1.z, x1.w);
    }
    out[(size_t)tk * 1024 + slot] = v;
}

// ---------------------------------------------------------------------------
// Persistent-A MFMA GEMM (NT): C[M,512] = A[M,512] @ B[512,512]^T.
// One block = one 128-row stripe, ALL 512 output cols. A (128x512 bf16,
// 128 KB) staged into LDS ONCE (SRC=0: fused fp32->bf16 reg conversion;
// SRC=1: global_load_lds from pre-tiled bf16). Then 32 steps s=(bn,kt):
// B-tile (16 KB, L2-hot) double-buffered with ONE __syncthreads per step;
// stage of B(s+1) issued before compute(s) -> L2 latency hides under MFMA.
// LDS: A [0,8192) uint4, B dbuf [8192,10240) = 160 KB total (1 block/CU).
// EPI 0: Cb[m*512+n]      = bf16(relu(acc+bias)-hist[m*512+n])
// EPI 1: Cb[m*1024+n]     = bf16((acc+bias)-hist[m*1024+n])
//        Cb[m*1024+512+n] = bf16(relu(acc+bias)-hist[m*1024+512+n])
// ---------------------------------------------------------------------------
template<int SRC, int EPI>
__global__ __launch_bounds__(256, 1)
void gemm_persist(const float* __restrict__ Af32, const uint4* __restrict__ At,
                  const uint4* __restrict__ Bt, const float* __restrict__ bias,
                  const float* __restrict__ hist, unsigned short* __restrict__ C,
                  int Mreal, int nblk)
{
    __shared__ uint4 lds[10240];   // A kt-tiles [0,8192), B dbuf [8192,10240)

    const int tid = threadIdx.x;
    // XCD-aware bijective swizzle (m204 general form); lid == bm here
    const int orig = blockIdx.x;
    const int xcd = orig & 7, q = nblk >> 3, rr = nblk & 7;
    const int bm = (xcd < rr ? xcd * (q + 1) : rr * (q + 1) + (xcd - rr) * q) + (orig >> 3);

    const int w = tid >> 6, lane = tid & 63;
    const int wm = w >> 1, wn = w & 1;
    const int lg = lane >> 4, lr = lane & 15;
    const int sw = lr & 7;

    // ---- stage A (once) ----
    if (SRC == 0) {
        // thread t: row r = t>>1, K-half = t&1 (k in [half*256, half*256+256))
        const int r = tid >> 1, half = tid & 1;
        int g = bm * 128 + r; if (g > Mreal - 1) g = Mreal - 1;  // clamp: rows>=M only affect unwritten C rows
        const float* Arow = Af32 + (size_t)g * 512 + half * 256;
        const int abase = r * 8;
        const int rsw = r & 7;
#pragma unroll 8
        for (int i = 0; i < 32; ++i) {
            float4 x0 = *(const float4*)(Arow + i * 8);
            float4 x1 = *(const float4*)(Arow + i * 8 + 4);
            uint4 v;
            v.x = pk_bf(x0.x, x0.y); v.y = pk_bf(x0.z, x0.w);
            v.z = pk_bf(x1.x, x1.y); v.w = pk_bf(x1.z, x1.w);
            const int kt = half * 4 + (i >> 3), o = i & 7;
            lds[kt * 1024 + abase + (o ^ rsw)] = v;
        }
    } else {
        const uint4* Ablk = At + (size_t)bm * 8192;
#pragma unroll
        for (int j = 0; j < 32; ++j) {
            const int slot = w * 2048 + j * 64 + lane;
            GLOAD_LDS(Ablk + slot, &lds[slot]);
        }
    }
    // ---- stage B step 0 (bn=0,kt=0) -> buf0 ----
    {
#pragma unroll
        for (int j = 0; j < 4; ++j) {
            const int slot = w * 256 + j * 64 + lane;
            GLOAD_LDS(Bt + slot, &lds[8192 + slot]);
        }
    }

    f32x4 acc[4][4];
#pragma unroll
    for (int i = 0; i < 4; ++i)
#pragma unroll
        for (int j = 0; j < 4; ++j) acc[i][j] = {0.f, 0.f, 0.f, 0.f};

    // ---- 32 steps: s = bn*8 + kt (B tiles are consecutive in memory) ----
    for (int s = 0; s < 32; ++s) {
        __syncthreads();   // drains B(s) (and A + lgkm at s=0)
        if (s < 31) {
            const uint4* Bn = Bt + (size_t)(s + 1) * 1024;
            const int bb = 8192 + ((s + 1) & 1) * 1024;
#pragma unroll
            for (int j = 0; j < 4; ++j) {
                const int slot = w * 256 + j * 64 + lane;
                GLOAD_LDS(Bn + slot, &lds[bb + slot]);
            }
        }
        const int kt = s & 7;
        const int bbase = 8192 + (s & 1) * 1024;

        bf16x8 a[4][2], b[4][2];
#pragma unroll
        for (int mi = 0; mi < 4; ++mi) {
            const uint4* rp = &lds[kt * 1024 + (wm * 64 + mi * 16 + lr) * 8];
            a[mi][0] = *(const bf16x8*)&rp[lg ^ sw];
            a[mi][1] = *(const bf16x8*)&rp[(4 + lg) ^ sw];
        }
#pragma unroll
        for (int ni = 0; ni < 4; ++ni) {
            const uint4* bp = &lds[bbase + (wn * 64 + ni * 16 + lr) * 8];
            b[ni][0] = *(const bf16x8*)&bp[lg ^ sw];
            b[ni][1] = *(const bf16x8*)&bp[(4 + lg) ^ sw];
        }
#pragma unroll
        for (int kk = 0; kk < 2; ++kk)
#pragma unroll
            for (int mi = 0; mi < 4; ++mi)
#pragma unroll
                for (int ni = 0; ni < 4; ++ni)
                    acc[mi][ni] = __builtin_amdgcn_mfma_f32_16x16x32_bf16(
                        a[mi][kk], b[ni][kk], acc[mi][ni], 0, 0, 0);

        if ((s & 7) == 7) {
            // epilogue for bn = s>>3; C/D layout col=lane&15, row=(lane>>4)*4+reg (m89)
            const int bn = s >> 3;
#pragma unroll
            for (int mi = 0; mi < 4; ++mi)
#pragma unroll
                for (int ni = 0; ni < 4; ++ni) {
                    const int col = bn * 128 + wn * 64 + ni * 16 + lr;
                    const float bv = bias[col];
#pragma unroll
                    for (int r = 0; r < 4; ++r) {
                        const int m = bm * 128 + wm * 64 + mi * 16 + lg * 4 + r;
                        if (m < Mreal) {
                            const float v = acc[mi][ni][r] + bv;
                            if (EPI == 0) {
                                C[(size_t)m * 512 + col] = to_bf(fmaxf(v, 0.f) - hist[(size_t)m * 512 + col]);
                            } else {
                                C[(size_t)m * 1024 + col]       = to_bf(v - hist[(size_t)m * 1024 + col]);
                                C[(size_t)m * 1024 + 512 + col] = to_bf(fmaxf(v, 0.f) - hist[(size_t)m * 1024 + 512 + col]);
                            }
                        }
                        acc[mi][ni][r] = 0.f;
                    }
                }
        }
    }
}

// ---------------------------------------------------------------------------
// Small GEMM: out[M,64] = A[M,1024] @ B[64,1024]^T + bias  (fp32 classifier)
// ---------------------------------------------------------------------------
__global__ __launch_bounds__(256)
void gemm64(const float* __restrict__ A, const float* __restrict__ B,
            const float* __restrict__ bias, float* __restrict__ C, int M)
{
    const int K = 1024;
    __shared__ float As[32][68];
    __shared__ float Bs[32][68];
    const int tid = threadIdx.x;
    const int tx = tid & 15, ty = tid >> 4;
    const int lrow = tid >> 3;
    const int lk   = (tid & 7) * 4;
    const int bm = blockIdx.x;

    float acc[4][4];
#pragma unroll
    for (int i = 0; i < 4; ++i)
#pragma unroll
        for (int j = 0; j < 4; ++j) acc[i][j] = 0.f;

    int ar0 = bm * 64 + lrow;      if (ar0 > M - 1) ar0 = M - 1;
    int ar1 = bm * 64 + 32 + lrow; if (ar1 > M - 1) ar1 = M - 1;

    for (int kt = 0; kt < K; kt += 32) {
        float4 a0 = *(const float4*)(A + (size_t)ar0 * K + kt + lk);
        float4 a1 = *(const float4*)(A + (size_t)ar1 * K + kt + lk);
        float4 b0 = *(const float4*)(B + (size_t)lrow * K + kt + lk);
        float4 b1 = *(const float4*)(B + (size_t)(32 + lrow) * K + kt + lk);
        __syncthreads();
        As[lk+0][lrow]    = a0.x; As[lk+1][lrow]    = a0.y; As[lk+2][lrow]    = a0.z; As[lk+3][lrow]    = a0.w;
        As[lk+0][lrow+32] = a1.x; As[lk+1][lrow+32] = a1.y; As[lk+2][lrow+32] = a1.z; As[lk+3][lrow+32] = a1.w;
        Bs[lk+0][lrow]    = b0.x; Bs[lk+1][lrow]    = b0.y; Bs[lk+2][lrow]    = b0.z; Bs[lk+3][lrow]    = b0.w;
        Bs[lk+0][lrow+32] = b1.x; Bs[lk+1][lrow+32] = b1.y; Bs[lk+2][lrow+32] = b1.z; Bs[lk+3][lrow+32] = b1.w;
        __syncthreads();
#pragma unroll
        for (int kk = 0; kk < 32; ++kk) {
            float4 av = *(const float4*)&As[kk][ty * 4];
            float4 bv = *(const float4*)&Bs[kk][tx * 4];
            float aa[4] = {av.x, av.y, av.z, av.w};
            float bb[4] = {bv.x, bv.y, bv.z, bv.w};
#pragma unroll
            for (int i = 0; i < 4; ++i)
#pragma unroll
                for (int j = 0; j < 4; ++j)
                    acc[i][j] += aa[i] * bb[j];
        }
    }

    const float4 bv = *(const float4*)&bias[tx * 4];
#pragma unroll
    for (int i = 0; i < 4; ++i) {
        const int m = bm * 64 + ty * 4 + i;
        if (m >= M) continue;
        float4 o;
        o.x = acc[i][0] + bv.x; o.y = acc[i][1] + bv.y;
        o.z = acc[i][2] + bv.z; o.w = acc[i][3] + bv.w;
        *(float4*)&C[(size_t)m * 64 + tx * 4] = o;
    }
}

// ---------------------------------------------------------------------------
// CSR build: degree count -> exclusive scan -> edge scatter
// ---------------------------------------------------------------------------
__global__ void count_deg(const int* __restrict__ dst, int* __restrict__ deg, int E)
{
    int e = blockIdx.x * blockDim.x + threadIdx.x;
    if (e < E) atomicAdd(&deg[dst[e]], 1);
}

__global__ __launch_bounds__(1024)
void exscan(const int* __restrict__ deg, int* __restrict__ off, int* __restrict__ cur, int n)
{
    __shared__ int wsum[16];
    __shared__ int carry;
    const int tid = threadIdx.x, lane = tid & 63, w = tid >> 6;
    if (tid == 0) carry = 0;
    __syncthreads();
    for (int base = 0; base < n; base += 1024) {
        const int i = base + tid;
        const int v = (i < n) ? deg[i] : 0;
        int x = v;
#pragma unroll
        for (int d = 1; d < 64; d <<= 1) {
            int y = __shfl_up(x, d, 64);
            if (lane >= d) x += y;
        }
        if (lane == 63) wsum[w] = x;
        __syncthreads();
        int wo = 0, tot = 0;
#pragma unroll
        for (int k = 0; k < 16; ++k) { int s = wsum[k]; tot += s; if (k < w) wo += s; }
        const int excl = carry + wo + x - v;
        if (i < n) { off[i] = excl; cur[i] = excl; }
        __syncthreads();
        if (tid == 0) carry += tot;
        __syncthreads();
    }
    if (tid == 0) off[n] = carry;
}

__global__ void scatter_edges(const int* __restrict__ src, const int* __restrict__ dst,
                              int* __restrict__ cur, int* __restrict__ eidx, int E)
{
    int e = blockIdx.x * blockDim.x + threadIdx.x;
    if (e < E) {
        int p = atomicAdd(&cur[dst[e]], 1);
        eidx[p] = src[e];
    }
}

// ---------------------------------------------------------------------------
// Segment mean over bf16 h (D=512) + fp32 residual add; writes bf16 tiled
// planes (GEMM2's A). One wave per dst row; lane owns k = lane*8..lane*8+7.
// ---------------------------------------------------------------------------
__global__ __launch_bounds__(256)
void seg_mean_split(const unsigned short* __restrict__ h, const int* __restrict__ off,
                    const int* __restrict__ eidx, const float* __restrict__ addin,
                    uint4* __restrict__ out, int n_dst, int n_pad)
{
    const int wid = blockIdx.x * 4 + (threadIdx.x >> 6);
    const int lane = threadIdx.x & 63;
    if (wid >= n_pad) return;
    uint4 v = {0u, 0u, 0u, 0u};
    if (wid < n_dst) {
        const int e0 = off[wid], e1 = off[wid + 1];
        float s[8];
#pragma unroll
        for (int i = 0; i < 8; ++i) s[i] = 0.f;
        for (int e = e0; e < e1; ++e) {
            const uint4 vv = *((const uint4*)(h + (size_t)eidx[e] * 512) + lane);
            const uint u[4] = {vv.x, vv.y, vv.z, vv.w};
#pragma unroll
            for (int i = 0; i < 4; ++i) {
                s[2 * i]     += __uint_as_float(u[i] << 16);
                s[2 * i + 1] += __uint_as_float(u[i] & 0xFFFF0000u);
            }
        }
        const float sc = 1.0f / (float)((e1 - e0) > 0 ? (e1 - e0) : 1);
        const float* ad = addin + (size_t)wid * 512 + lane * 8;
        float4 d0 = *(const float4*)ad;
        float4 d1 = *(const float4*)(ad + 4);
        v.x = pk_bf(s[0] * sc + d0.x, s[1] * sc + d0.y);
        v.y = pk_bf(s[2] * sc + d0.z, s[3] * sc + d0.w);
        v.z = pk_bf(s[4] * sc + d1.x, s[5] * sc + d1.y);
        v.w = pk_bf(s[6] * sc + d1.z, s[7] * sc + d1.w);
    }
    // tiled layout: [mt*8 + kt8][r*8 + (o ^ (r&7))], kt8 = lane>>3, o = lane&7
    const int mt = wid >> 7, r = wid & 127;
    const int kt8 = lane >> 3, o = lane & 7;
    out[((size_t)(mt * 8 + kt8)) * 1024 + r * 8 + (o ^ (r & 7))] = v;
}

// ---------------------------------------------------------------------------
// Segment mean over bf16 h (D=1024) + fp32 residual add -> fp32 out (agg1)
// ---------------------------------------------------------------------------
__global__ __launch_bounds__(256)
void seg_mean_add4(const unsigned short* __restrict__ h, const int* __restrict__ off,
                   const int* __restrict__ eidx, const float* __restrict__ addin,
                   float* __restrict__ out, int n_dst)
{
    const int wid = blockIdx.x * 4 + (threadIdx.x >> 6);
    const int lane = threadIdx.x & 63;
    if (wid >= n_dst) return;
    const int e0 = off[wid], e1 = off[wid + 1];
    float s[16];
#pragma unroll
    for (int i = 0; i < 16; ++i) s[i] = 0.f;
    for (int e = e0; e < e1; ++e) {
        const uint4* row = (const uint4*)(h + (size_t)eidx[e] * 1024);
#pragma unroll
        for (int half = 0; half < 2; ++half) {
            const uint4 v = row[lane + 64 * half];
            const uint u[4] = {v.x, v.y, v.z, v.w};
#pragma unroll
            for (int i = 0; i < 4; ++i) {
                s[8 * half + 2 * i]     += __uint_as_float(u[i] << 16);
                s[8 * half + 2 * i + 1] += __uint_as_float(u[i] & 0xFFFF0000u);
            }
        }
    }
    const float sc = 1.0f / (float)((e1 - e0) > 0 ? (e1 - e0) : 1);
#pragma unroll
    for (int half = 0; half < 2; ++half) {
        const float* ad = addin + (size_t)wid * 1024 + half * 512 + lane * 8;
        float* o = out + (size_t)wid * 1024 + half * 512 + lane * 8;
        float4 d0 = *(const float4*)ad;
        float4 d1 = *(const float4*)(ad + 4);
        float4 r0, r1;
        r0.x = s[8*half+0] * sc + d0.x; r0.y = s[8*half+1] * sc + d0.y;
        r0.z = s[8*half+2] * sc + d0.z; r0.w = s[8*half+3] * sc + d0.w;
        r1.x = s[8*half+4] * sc + d1.x; r1.y = s[8*half+5] * sc + d1.y;
        r1.z = s[8*half+6] * sc + d1.z; r1.w = s[8*half+7] * sc + d1.w;
        *(float4*)o = r0;
        *(float4*)(o + 4) = r1;
    }
}

// ---------------------------------------------------------------------------
extern "C" void kernel_launch(void* const* d_in, const int* in_sizes, int n_in,
                              void* d_out, int out_size, void* d_ws, size_t ws_size,
                              hipStream_t stream)
{
    const float* feats   = (const float*)d_in[0];
    const float* h0_hist = (const float*)d_in[1];
    const float* agg_h0  = (const float*)d_in[2];
    const float* h1_hist = (const float*)d_in[3];
    const float* agg_h1  = (const float*)d_in[4];
    const float* W0 = (const float*)d_in[5];
    const float* b0 = (const float*)d_in[6];
    const float* W1 = (const float*)d_in[7];
    const float* b1 = (const float*)d_in[8];
    const float* W2 = (const float*)d_in[9];
    const float* b2 = (const float*)d_in[10];
    const int* src0 = (const int*)d_in[11];
    const int* dst0 = (const int*)d_in[12];
    const int* src1 = (const int*)d_in[13];
    const int* dst1 = (const int*)d_in[14];

    const int MT1 = 782;                       // ceil(100000/128)
    const int MT2 = 196;                       // ceil(25000/128)
    const size_t TILEB = 8 * 1024 * 16;        // 128 KiB per M-tile (8 kt x 16KB)

    const size_t h0B   = ((size_t)N0c * 512 * 2 + 255) & ~(size_t)255;   // bf16 h0 (h1cat overlays)
    const size_t a2B   = (size_t)MT2 * TILEB;                            // 25.7 MB
    const size_t agg1B = (size_t)N2c * 1024 * 4;                         // 20.5 MB
    const size_t wsB   = 4 * 8 * 1024 * 16;                              // 512 KB per weight plane

    char* ws = (char*)d_ws;
    unsigned short* h0 = (unsigned short*)ws;
    unsigned short* h1cat = h0;                              ws += h0B;
    uint4* A2s    = (uint4*)ws;                              ws += a2B;
    float* agg1   = (float*)ws;                              ws += agg1B;
    uint4* Ws0    = (uint4*)ws;                              ws += wsB;
    uint4* Ws1    = (uint4*)ws;                              ws += wsB;
    int* deg0  = (int*)ws;  ws += sizeof(int) * N1c;
    int* off0  = (int*)ws;  ws += sizeof(int) * (N1c + 1);
    int* cur0  = (int*)ws;  ws += sizeof(int) * N1c;
    int* eidx0 = (int*)ws;  ws += sizeof(int) * E0c;
    int* deg1  = (int*)ws;  ws += sizeof(int) * N2c;
    int* off1  = (int*)ws;  ws += sizeof(int) * (N2c + 1);
    int* cur1  = (int*)ws;  ws += sizeof(int) * N2c;
    int* eidx1 = (int*)ws;

    hipMemsetAsync(deg0, 0, sizeof(int) * N1c, stream);
    hipMemsetAsync(deg1, 0, sizeof(int) * N2c, stream);

    // weight planes + CSR level 0 (independent of GEMM1)
    presplit_bf<<<4 * 32, 256, 0, stream>>>(W0, Ws0, 512, 0, 4);
    presplit_bf<<<4 * 32, 256, 0, stream>>>(W1, Ws1, 512, 0, 4);
    count_deg<<<(E0c + 255) / 256, 256, 0, stream>>>(dst0, deg0, E0c);
    exscan<<<1, 1024, 0, stream>>>(deg0, off0, cur0, N1c);
    scatter_edges<<<(E0c + 255) / 256, 256, 0, stream>>>(src0, dst0, cur0, eidx0, E0c);

    // layer 0: h0 = bf16(relu(feats @ W0^T + b0) - h0_hist)  (fused fp32->bf16 A-stage)
    gemm_persist<0, 0><<<MT1, 256, 0, stream>>>(feats, nullptr, Ws0, b0, h0_hist, h0, N0c, MT1);

    // agg0 = segment_mean(h0) + agg_h0, written as bf16 tiled planes
    seg_mean_split<<<(MT2 * 128) / 4, 256, 0, stream>>>(h0, off0, eidx0, agg_h0, A2s, N1c, MT2 * 128);

    // CSR level 1
    count_deg<<<(E1c + 255) / 256, 256, 0, stream>>>(dst1, deg1, E1c);
    exscan<<<1, 1024, 0, stream>>>(deg1, off1, cur1, N2c);
    scatter_edges<<<(E1c + 255) / 256, 256, 0, stream>>>(src1, dst1, cur1, eidx1, E1c);

    // layer 1: h1cat = bf16([h1 | relu(h1)] - h1_hist), h1 = agg0 @ W1^T + b1
    gemm_persist<1, 1><<<MT2, 256, 0, stream>>>(nullptr, A2s, Ws1, b1, h1_hist, h1cat, N1c, MT2);

    // agg1 = segment_mean(h1cat) + agg_h1  (fp32)
    seg_mean_add4<<<(N2c + 3) / 4, 256, 0, stream>>>(h1cat, off1, eidx1, agg_h1, agg1, N2c);

    // classifier: out = agg1 @ W2^T + b2
    gemm64<<<(N2c + 63) / 64, 256, 0, stream>>>(agg1, W2, b2, (float*)d_out, N2c);
}

// Round 8
// 639.036 us; speedup vs baseline: 1.4356x; 1.4356x over previous
//
#include <hip/hip_runtime.h>

#define N0c 100000
#define N1c 25000
#define N2c 5000
#define E0c 400000
#define E1c 80000
// IN_FEATS = N_HIDDEN = 512, N_CLASSES = 64
// M-tiles (128 rows): GEMM1 782, GEMM2 196

typedef __attribute__((ext_vector_type(8))) short bf16x8;
typedef __attribute__((ext_vector_type(4))) float f32x4;

#define GLOAD_LDS(g, l) \
    __builtin_amdgcn_global_load_lds((__attribute__((address_space(1))) const unsigned int*)(const void*)(g), \
                                     (__attribute__((address_space(3))) unsigned int*)(void*)(l), 16, 0, 0)

// round-to-nearest-even bf16, returned as fp32 bit pattern (low 16 zeroed)
static __device__ __forceinline__ uint rnd_bf(float f) {
    uint u = __float_as_uint(f);
    return (u + 0x7FFFu + ((u >> 16) & 1u)) & 0xFFFF0000u;
}
static __device__ __forceinline__ unsigned short to_bf(float f) {
    return (unsigned short)(rnd_bf(f) >> 16);
}
// pack two floats -> one uint holding 2 bf16 (low = f0, high = f1)
static __device__ __forceinline__ uint pk_bf(float f0, float f1) {
    return (rnd_bf(f0) >> 16) | rnd_bf(f1);
}

// ---------------------------------------------------------------------------
// Pre-convert (weights only): X[512][512] fp32 -> bf16 tiled planes.
// Tile = 128 rows x 64 k = 16 KiB: [r=128][p=8 x 16B slots], physical slot
// p holds k-octet o = p ^ (r&7) (k = kt*64 + o*8). Buffer [mt*8+kt][1024].
// ---------------------------------------------------------------------------
__global__ __launch_bounds__(256)
void presplit_bf(const float* __restrict__ X, uint4* __restrict__ out,
                 int M, int tile0, int ntiles)
{
    const int id = blockIdx.x * 256 + threadIdx.x;
    const int slot = id & 1023;            // r*8 + p
    const int tk = id >> 10;               // mtl*8 + kt
    if (tk >= ntiles * 8) return;
    const int kt8 = tk & 7, mtl = tk >> 3;
    const int r = slot >> 3, p = slot & 7;
    const int o = p ^ (r & 7);
    const int row = (tile0 + mtl) * 128 + r;
    uint4 v = {0u, 0u, 0u, 0u};
    if (row < M) {
        const float* src = X + (size_t)row * 512 + kt8 * 64 + o * 8;
        float4 x0 = *(const float4*)src;
        float4 x1 = *(const float4*)(src + 4);
        v.x = pk_bf(x0.x, x0.y); v.y = pk_bf(x0.z, x0.w);
        v.z = pk_bf(x1.x, x1.y); v.w = pk_bf(x1.z, x1.w);
    }
    out[(size_t)tk * 1024 + slot] = v;
}

// ---------------------------------------------------------------------------
// bf16 MFMA GEMM (NT): C[M,512] = A[M,512] @ B[512,512]^T.
// Tile 128x256, 8 waves (2M x 4N), BK=64, single 48-KB LDS buffer
// (A [0,1024) uint4, B [1024,3072)), R6's proven 2-barrier K-loop.
// 3 blocks/CU (144KB LDS) -> 24 waves/CU TLP.
// SRC 0: A staged from fp32 (in-reg bf16 convert, conflict-free ds_write:
//        8 lanes cover all 8 slots of one row = full 128B = all 32 banks).
// SRC 1: A staged via global_load_lds from pre-tiled bf16 planes.
// EPI 0: Cb[m*512+n]      = bf16(relu(acc+bias)-hist[m*512+n])
// EPI 1: Cb[m*1024+n]     = bf16((acc+bias)-hist[m*1024+n])
//        Cb[m*1024+512+n] = bf16(relu(acc+bias)-hist[m*1024+512+n])
// ---------------------------------------------------------------------------
template<int SRC, int EPI>
__global__ __launch_bounds__(512, 2)
void gemm_half(const float* __restrict__ Af32, const uint4* __restrict__ At,
               const uint4* __restrict__ Bt, const float* __restrict__ bias,
               const float* __restrict__ hist, unsigned short* __restrict__ C,
               int Mreal, int nblk)
{
    __shared__ uint4 lds[3072];   // A [0,1024), B [1024,3072)

    const int tid = threadIdx.x;
    // XCD-aware bijective swizzle (m204 general form)
    const int orig = blockIdx.x;
    const int xcd = orig & 7, q = nblk >> 3, rr = nblk & 7;
    const int lid = (xcd < rr ? xcd * (q + 1) : rr * (q + 1) + (xcd - rr) * q) + (orig >> 3);
    const int bm = lid >> 1, bnh = lid & 1;   // bnh = which 256-col half

    const int w = tid >> 6, lane = tid & 63;
    const int wm = w >> 2, wn = w & 3;        // wave grid 2M x 4N
    const int lg = lane >> 4, lr = lane & 15;
    const int sw = lr & 15 & 7;

    // A fp32 staging coords (SRC==0): 8 lanes per row -> all 8 slots
    const int ar = tid >> 3;                  // 0..63
    const int as = tid & 7;                   // physical slot

    f32x4 acc[4][4];
#pragma unroll
    for (int i = 0; i < 4; ++i)
#pragma unroll
        for (int j = 0; j < 4; ++j) acc[i][j] = {0.f, 0.f, 0.f, 0.f};

    for (int kt = 0; kt < 8; ++kt) {
        if (kt) __syncthreads();          // all waves done reading LDS
        // ---- stage A tile (128 rows x 64 k bf16 = 16 KB) ----
        if (SRC == 0) {
#pragma unroll
            for (int u = 0; u < 2; ++u) {
                const int r = ar + u * 64;
                const int o = as ^ (r & 7);
                int g = bm * 128 + r; if (g > Mreal - 1) g = Mreal - 1;
                const float* p = Af32 + (size_t)g * 512 + kt * 64 + o * 8;
                float4 x0 = *(const float4*)p;
                float4 x1 = *(const float4*)(p + 4);
                uint4 v;
                v.x = pk_bf(x0.x, x0.y); v.y = pk_bf(x0.z, x0.w);
                v.z = pk_bf(x1.x, x1.y); v.w = pk_bf(x1.z, x1.w);
                lds[r * 8 + as] = v;      // linear slot -> conflict-free
            }
        } else {
            const uint4* Ablk = At + ((size_t)bm * 8 + kt) * 1024;
            GLOAD_LDS(Ablk + tid, &lds[tid]);
            GLOAD_LDS(Ablk + 512 + tid, &lds[512 + tid]);
        }
        // ---- stage B tile (256 rows x 64 k bf16 = 32 KB, L2-hot) ----
#pragma unroll
        for (int j = 0; j < 4; ++j) {
            const int sl = w * 256 + j * 64 + lane;     // 0..2047
            const int sub = sl >> 10;                   // which 128-row subtile
            const int off = sl & 1023;
            GLOAD_LDS(Bt + ((size_t)(2 * bnh + sub) * 8 + kt) * 1024 + off,
                      &lds[1024 + sl]);
        }
        __syncthreads();                  // compiler drains vmcnt+lgkm here

        bf16x8 a[4][2], b[4][2];
#pragma unroll
        for (int mi = 0; mi < 4; ++mi) {
            const uint4* rp = &lds[(wm * 64 + mi * 16 + lr) * 8];
            a[mi][0] = *(const bf16x8*)&rp[lg ^ sw];
            a[mi][1] = *(const bf16x8*)&rp[(4 + lg) ^ sw];
        }
#pragma unroll
        for (int ni = 0; ni < 4; ++ni) {
            const uint4* rp = &lds[1024 + (wn * 64 + ni * 16 + lr) * 8];
            b[ni][0] = *(const bf16x8*)&rp[lg ^ sw];
            b[ni][1] = *(const bf16x8*)&rp[(4 + lg) ^ sw];
        }
#pragma unroll
        for (int kk = 0; kk < 2; ++kk)
#pragma unroll
            for (int mi = 0; mi < 4; ++mi)
#pragma unroll
                for (int ni = 0; ni < 4; ++ni)
                    acc[mi][ni] = __builtin_amdgcn_mfma_f32_16x16x32_bf16(
                        a[mi][kk], b[ni][kk], acc[mi][ni], 0, 0, 0);
    }

    // epilogue: C/D layout col=lane&15, row=(lane>>4)*4+reg  (m89)
#pragma unroll
    for (int mi = 0; mi < 4; ++mi)
#pragma unroll
        for (int ni = 0; ni < 4; ++ni) {
            const int col = bnh * 256 + wn * 64 + ni * 16 + lr;
            const float bv = bias[col];
#pragma unroll
            for (int r = 0; r < 4; ++r) {
                const int m = bm * 128 + wm * 64 + mi * 16 + lg * 4 + r;
                if (m < Mreal) {
                    const float v = acc[mi][ni][r] + bv;
                    if (EPI == 0) {
                        C[(size_t)m * 512 + col] = to_bf(fmaxf(v, 0.f) - hist[(size_t)m * 512 + col]);
                    } else {
                        C[(size_t)m * 1024 + col]       = to_bf(v - hist[(size_t)m * 1024 + col]);
                        C[(size_t)m * 1024 + 512 + col] = to_bf(fmaxf(v, 0.f) - hist[(size_t)m * 1024 + 512 + col]);
                    }
                }
            }
        }
}

// ---------------------------------------------------------------------------
// Small GEMM: out[M,64] = A[M,1024] @ B[64,1024]^T + bias  (fp32 classifier)
// ---------------------------------------------------------------------------
__global__ __launch_bounds__(256)
void gemm64(const float* __restrict__ A, const float* __restrict__ B,
            const float* __restrict__ bias, float* __restrict__ C, int M)
{
    const int K = 1024;
    __shared__ float As[32][68];
    __shared__ float Bs[32][68];
    const int tid = threadIdx.x;
    const int tx = tid & 15, ty = tid >> 4;
    const int lrow = tid >> 3;
    const int lk   = (tid & 7) * 4;
    const int bm = blockIdx.x;

    float acc[4][4];
#pragma unroll
    for (int i = 0; i < 4; ++i)
#pragma unroll
        for (int j = 0; j < 4; ++j) acc[i][j] = 0.f;

    int ar0 = bm * 64 + lrow;      if (ar0 > M - 1) ar0 = M - 1;
    int ar1 = bm * 64 + 32 + lrow; if (ar1 > M - 1) ar1 = M - 1;

    for (int kt = 0; kt < K; kt += 32) {
        float4 a0 = *(const float4*)(A + (size_t)ar0 * K + kt + lk);
        float4 a1 = *(const float4*)(A + (size_t)ar1 * K + kt + lk);
        float4 b0 = *(const float4*)(B + (size_t)lrow * K + kt + lk);
        float4 b1 = *(const float4*)(B + (size_t)(32 + lrow) * K + kt + lk);
        __syncthreads();
        As[lk+0][lrow]    = a0.x; As[lk+1][lrow]    = a0.y; As[lk+2][lrow]    = a0.z; As[lk+3][lrow]    = a0.w;
        As[lk+0][lrow+32] = a1.x; As[lk+1][lrow+32] = a1.y; As[lk+2][lrow+32] = a1.z; As[lk+3][lrow+32] = a1.w;
        Bs[lk+0][lrow]    = b0.x; Bs[lk+1][lrow]    = b0.y; Bs[lk+2][lrow]    = b0.z; Bs[lk+3][lrow]    = b0.w;
        Bs[lk+0][lrow+32] = b1.x; Bs[lk+1][lrow+32] = b1.y; Bs[lk+2][lrow+32] = b1.z; Bs[lk+3][lrow+32] = b1.w;
        __syncthreads();
#pragma unroll
        for (int kk = 0; kk < 32; ++kk) {
            float4 av = *(const float4*)&As[kk][ty * 4];
            float4 bv = *(const float4*)&Bs[kk][tx * 4];
            float aa[4] = {av.x, av.y, av.z, av.w};
            float bb[4] = {bv.x, bv.y, bv.z, bv.w};
#pragma unroll
            for (int i = 0; i < 4; ++i)
#pragma unroll
                for (int j = 0; j < 4; ++j)
                    acc[i][j] += aa[i] * bb[j];
        }
    }

    const float4 bv = *(const float4*)&bias[tx * 4];
#pragma unroll
    for (int i = 0; i < 4; ++i) {
        const int m = bm * 64 + ty * 4 + i;
        if (m >= M) continue;
        float4 o;
        o.x = acc[i][0] + bv.x; o.y = acc[i][1] + bv.y;
        o.z = acc[i][2] + bv.z; o.w = acc[i][3] + bv.w;
        *(float4*)&C[(size_t)m * 64 + tx * 4] = o;
    }
}

// ---------------------------------------------------------------------------
// CSR build: degree count -> exclusive scan -> edge scatter
// ---------------------------------------------------------------------------
__global__ void count_deg(const int* __restrict__ dst, int* __restrict__ deg, int E)
{
    int e = blockIdx.x * blockDim.x + threadIdx.x;
    if (e < E) atomicAdd(&deg[dst[e]], 1);
}

__global__ __launch_bounds__(1024)
void exscan(const int* __restrict__ deg, int* __restrict__ off, int* __restrict__ cur, int n)
{
    __shared__ int wsum[16];
    __shared__ int carry;
    const int tid = threadIdx.x, lane = tid & 63, w = tid >> 6;
    if (tid == 0) carry = 0;
    __syncthreads();
    for (int base = 0; base < n; base += 1024) {
        const int i = base + tid;
        const int v = (i < n) ? deg[i] : 0;
        int x = v;
#pragma unroll
        for (int d = 1; d < 64; d <<= 1) {
            int y = __shfl_up(x, d, 64);
            if (lane >= d) x += y;
        }
        if (lane == 63) wsum[w] = x;
        __syncthreads();
        int wo = 0, tot = 0;
#pragma unroll
        for (int k = 0; k < 16; ++k) { int s = wsum[k]; tot += s; if (k < w) wo += s; }
        const int excl = carry + wo + x - v;
        if (i < n) { off[i] = excl; cur[i] = excl; }
        __syncthreads();
        if (tid == 0) carry += tot;
        __syncthreads();
    }
    if (tid == 0) off[n] = carry;
}

__global__ void scatter_edges(const int* __restrict__ src, const int* __restrict__ dst,
                              int* __restrict__ cur, int* __restrict__ eidx, int E)
{
    int e = blockIdx.x * blockDim.x + threadIdx.x;
    if (e < E) {
        int p = atomicAdd(&cur[dst[e]], 1);
        eidx[p] = src[e];
    }
}

// ---------------------------------------------------------------------------
// Segment mean over bf16 h (D=512) + fp32 residual add; writes bf16 tiled
// planes (GEMM2's A). One wave per dst row; lane owns k = lane*8..lane*8+7.
// ---------------------------------------------------------------------------
__global__ __launch_bounds__(256)
void seg_mean_split(const unsigned short* __restrict__ h, const int* __restrict__ off,
                    const int* __restrict__ eidx, const float* __restrict__ addin,
                    uint4* __restrict__ out, int n_dst, int n_pad)
{
    const int wid = blockIdx.x * 4 + (threadIdx.x >> 6);
    const int lane = threadIdx.x & 63;
    if (wid >= n_pad) return;
    uint4 v = {0u, 0u, 0u, 0u};
    if (wid < n_dst) {
        const int e0 = off[wid], e1 = off[wid + 1];
        float s[8];
#pragma unroll
        for (int i = 0; i < 8; ++i) s[i] = 0.f;
        for (int e = e0; e < e1; ++e) {
            const uint4 vv = *((const uint4*)(h + (size_t)eidx[e] * 512) + lane);
            const uint u[4] = {vv.x, vv.y, vv.z, vv.w};
#pragma unroll
            for (int i = 0; i < 4; ++i) {
                s[2 * i]     += __uint_as_float(u[i] << 16);
                s[2 * i + 1] += __uint_as_float(u[i] & 0xFFFF0000u);
            }
        }
        const float sc = 1.0f / (float)((e1 - e0) > 0 ? (e1 - e0) : 1);
        const float* ad = addin + (size_t)wid * 512 + lane * 8;
        float4 d0 = *(const float4*)ad;
        float4 d1 = *(const float4*)(ad + 4);
        v.x = pk_bf(s[0] * sc + d0.x, s[1] * sc + d0.y);
        v.y = pk_bf(s[2] * sc + d0.z, s[3] * sc + d0.w);
        v.z = pk_bf(s[4] * sc + d1.x, s[5] * sc + d1.y);
        v.w = pk_bf(s[6] * sc + d1.z, s[7] * sc + d1.w);
    }
    // tiled layout: [mt*8 + kt8][r*8 + (o ^ (r&7))], kt8 = lane>>3, o = lane&7
    const int mt = wid >> 7, r = wid & 127;
    const int kt8 = lane >> 3, o = lane & 7;
    out[((size_t)(mt * 8 + kt8)) * 1024 + r * 8 + (o ^ (r & 7))] = v;
}

// ---------------------------------------------------------------------------
// Segment mean over bf16 h (D=1024) + fp32 residual add -> fp32 out (agg1)
// ---------------------------------------------------------------------------
__global__ __launch_bounds__(256)
void seg_mean_add4(const unsigned short* __restrict__ h, const int* __restrict__ off,
                   const int* __restrict__ eidx, const float* __restrict__ addin,
                   float* __restrict__ out, int n_dst)
{
    const int wid = blockIdx.x * 4 + (threadIdx.x >> 6);
    const int lane = threadIdx.x & 63;
    if (wid >= n_dst) return;
    const int e0 = off[wid], e1 = off[wid + 1];
    float s[16];
#pragma unroll
    for (int i = 0; i < 16; ++i) s[i] = 0.f;
    for (int e = e0; e < e1; ++e) {
        const uint4* row = (const uint4*)(h + (size_t)eidx[e] * 1024);
#pragma unroll
        for (int half = 0; half < 2; ++half) {
            const uint4 v = row[lane + 64 * half];
            const uint u[4] = {v.x, v.y, v.z, v.w};
#pragma unroll
            for (int i = 0; i < 4; ++i) {
                s[8 * half + 2 * i]     += __uint_as_float(u[i] << 16);
                s[8 * half + 2 * i + 1] += __uint_as_float(u[i] & 0xFFFF0000u);
            }
        }
    }
    const float sc = 1.0f / (float)((e1 - e0) > 0 ? (e1 - e0) : 1);
#pragma unroll
    for (int half = 0; half < 2; ++half) {
        const float* ad = addin + (size_t)wid * 1024 + half * 512 + lane * 8;
        float* o = out + (size_t)wid * 1024 + half * 512 + lane * 8;
        float4 d0 = *(const float4*)ad;
        float4 d1 = *(const float4*)(ad + 4);
        float4 r0, r1;
        r0.x = s[8*half+0] * sc + d0.x; r0.y = s[8*half+1] * sc + d0.y;
        r0.z = s[8*half+2] * sc + d0.z; r0.w = s[8*half+3] * sc + d0.w;
        r1.x = s[8*half+4] * sc + d1.x; r1.y = s[8*half+5] * sc + d1.y;
        r1.z = s[8*half+6] * sc + d1.z; r1.w = s[8*half+7] * sc + d1.w;
        *(float4*)o = r0;
        *(float4*)(o + 4) = r1;
    }
}

// ---------------------------------------------------------------------------
extern "C" void kernel_launch(void* const* d_in, const int* in_sizes, int n_in,
                              void* d_out, int out_size, void* d_ws, size_t ws_size,
                              hipStream_t stream)
{
    const float* feats   = (const float*)d_in[0];
    const float* h0_hist = (const float*)d_in[1];
    const float* agg_h0  = (const float*)d_in[2];
    const float* h1_hist = (const float*)d_in[3];
    const float* agg_h1  = (const float*)d_in[4];
    const float* W0 = (const float*)d_in[5];
    const float* b0 = (const float*)d_in[6];
    const float* W1 = (const float*)d_in[7];
    const float* b1 = (const float*)d_in[8];
    const float* W2 = (const float*)d_in[9];
    const float* b2 = (const float*)d_in[10];
    const int* src0 = (const int*)d_in[11];
    const int* dst0 = (const int*)d_in[12];
    const int* src1 = (const int*)d_in[13];
    const int* dst1 = (const int*)d_in[14];

    const int MT1 = 782;                       // ceil(100000/128)
    const int MT2 = 196;                       // ceil(25000/128)
    const size_t TILEB = 8 * 1024 * 16;        // 128 KiB per M-tile (8 kt x 16KB)

    const size_t h0B   = ((size_t)N0c * 512 * 2 + 255) & ~(size_t)255;   // bf16 h0 (h1cat overlays)
    const size_t a2B   = (size_t)MT2 * TILEB;                            // 25.7 MB
    const size_t agg1B = (size_t)N2c * 1024 * 4;                         // 20.5 MB
    const size_t wsB   = 4 * 8 * 1024 * 16;                              // 512 KB per weight plane

    char* ws = (char*)d_ws;
    unsigned short* h0 = (unsigned short*)ws;
    unsigned short* h1cat = h0;                              ws += h0B;
    uint4* A2s    = (uint4*)ws;                              ws += a2B;
    float* agg1   = (float*)ws;                              ws += agg1B;
    uint4* Ws0    = (uint4*)ws;                              ws += wsB;
    uint4* Ws1    = (uint4*)ws;                              ws += wsB;
    int* deg0  = (int*)ws;  ws += sizeof(int) * N1c;
    int* off0  = (int*)ws;  ws += sizeof(int) * (N1c + 1);
    int* cur0  = (int*)ws;  ws += sizeof(int) * N1c;
    int* eidx0 = (int*)ws;  ws += sizeof(int) * E0c;
    int* deg1  = (int*)ws;  ws += sizeof(int) * N2c;
    int* off1  = (int*)ws;  ws += sizeof(int) * (N2c + 1);
    int* cur1  = (int*)ws;  ws += sizeof(int) * N2c;
    int* eidx1 = (int*)ws;

    hipMemsetAsync(deg0, 0, sizeof(int) * N1c, stream);
    hipMemsetAsync(deg1, 0, sizeof(int) * N2c, stream);

    // weight planes + CSR level 0 (independent of GEMM1)
    presplit_bf<<<4 * 32, 256, 0, stream>>>(W0, Ws0, 512, 0, 4);
    presplit_bf<<<4 * 32, 256, 0, stream>>>(W1, Ws1, 512, 0, 4);
    count_deg<<<(E0c + 255) / 256, 256, 0, stream>>>(dst0, deg0, E0c);
    exscan<<<1, 1024, 0, stream>>>(deg0, off0, cur0, N1c);
    scatter_edges<<<(E0c + 255) / 256, 256, 0, stream>>>(src0, dst0, cur0, eidx0, E0c);

    // layer 0: h0 = bf16(relu(feats @ W0^T + b0) - h0_hist)
    // A converted fp32->bf16 in-kernel (no presplit pass for feats)
    gemm_half<0, 0><<<MT1 * 2, 512, 0, stream>>>(feats, nullptr, Ws0, b0, h0_hist, h0, N0c, MT1 * 2);

    // agg0 = segment_mean(h0) + agg_h0, written as bf16 tiled planes
    seg_mean_split<<<(MT2 * 128) / 4, 256, 0, stream>>>(h0, off0, eidx0, agg_h0, A2s, N1c, MT2 * 128);

    // CSR level 1
    count_deg<<<(E1c + 255) / 256, 256, 0, stream>>>(dst1, deg1, E1c);
    exscan<<<1, 1024, 0, stream>>>(deg1, off1, cur1, N2c);
    scatter_edges<<<(E1c + 255) / 256, 256, 0, stream>>>(src1, dst1, cur1, eidx1, E1c);

    // layer 1: h1cat = bf16([h1 | relu(h1)] - h1_hist), h1 = agg0 @ W1^T + b1
    gemm_half<1, 1><<<MT2 * 2, 512, 0, stream>>>(nullptr, A2s, Ws1, b1, h1_hist, h1cat, N1c, MT2 * 2);

    // agg1 = segment_mean(h1cat) + agg_h1  (fp32)
    seg_mean_add4<<<(N2c + 3) / 4, 256, 0, stream>>>(h1cat, off1, eidx1, agg_h1, agg1, N2c);

    // classifier: out = agg1 @ W2^T + b2
    gemm64<<<(N2c + 63) / 64, 256, 0, stream>>>(agg1, W2, b2, (float*)d_out, N2c);
}

// Round 9
// 594.621 us; speedup vs baseline: 1.5428x; 1.0747x over previous
//
#include <hip/hip_runtime.h>

#define N0c 100000
#define N1c 25000
#define N2c 5000
#define E0c 400000
#define E1c 80000
// IN_FEATS = N_HIDDEN = 512, N_CLASSES = 64
// M-tiles (128 rows): GEMM1 782, GEMM2 196

typedef __attribute__((ext_vector_type(8))) short bf16x8;
typedef __attribute__((ext_vector_type(4))) float f32x4;

#define GLOAD_LDS(g, l) \
    __builtin_amdgcn_global_load_lds((__attribute__((address_space(1))) const unsigned int*)(const void*)(g), \
                                     (__attribute__((address_space(3))) unsigned int*)(void*)(l), 16, 0, 0)

// round-to-nearest-even bf16, returned as fp32 bit pattern (low 16 zeroed)
static __device__ __forceinline__ uint rnd_bf(float f) {
    uint u = __float_as_uint(f);
    return (u + 0x7FFFu + ((u >> 16) & 1u)) & 0xFFFF0000u;
}
static __device__ __forceinline__ unsigned short to_bf(float f) {
    return (unsigned short)(rnd_bf(f) >> 16);
}
// pack two floats -> one uint holding 2 bf16 (low = f0, high = f1)
static __device__ __forceinline__ uint pk_bf(float f0, float f1) {
    return (rnd_bf(f0) >> 16) | rnd_bf(f1);
}

// ---------------------------------------------------------------------------
// Pre-convert: X[M][512] fp32 -> bf16 tiled planes (layout == GEMM LDS).
// Tile = 128 rows x 64 k = 16 KiB: [r=128][p=8 x 16B slots], physical slot
// p holds k-octet o = p ^ (r&7) (k = kt*64 + o*8). Buffer [mtl*8+kt][1024].
// Rows >= M zeroed. Linear writes.
// ---------------------------------------------------------------------------
__global__ __launch_bounds__(256)
void presplit_bf(const float* __restrict__ X, uint4* __restrict__ out,
                 int M, int tile0, int ntiles)
{
    const int id = blockIdx.x * 256 + threadIdx.x;
    const int slot = id & 1023;            // r*8 + p
    const int tk = id >> 10;               // mtl*8 + kt
    if (tk >= ntiles * 8) return;
    const int kt8 = tk & 7, mtl = tk >> 3;
    const int r = slot >> 3, p = slot & 7;
    const int o = p ^ (r & 7);
    const int row = (tile0 + mtl) * 128 + r;
    uint4 v = {0u, 0u, 0u, 0u};
    if (row < M) {
        const float* src = X + (size_t)row * 512 + kt8 * 64 + o * 8;
        float4 x0 = *(const float4*)src;
        float4 x1 = *(const float4*)(src + 4);
        v.x = pk_bf(x0.x, x0.y); v.y = pk_bf(x0.z, x0.w);
        v.z = pk_bf(x1.x, x1.y); v.w = pk_bf(x1.z, x1.w);
    }
    out[(size_t)tk * 1024 + slot] = v;
}

// ---------------------------------------------------------------------------
// bf16 MFMA GEMM (NT): C[M,512] = A[M,512] @ B[512,512]^T.
// Tile 128x256, 8 waves (2M x 4N), BK=64, single 48-KB LDS buffer,
// R6's proven 2-barrier K-loop, ALL staging via global_load_lds from
// pre-tiled bf16 planes (A amplification 2x, no VGPR round-trip).
// 3 blocks/CU (144 KB LDS) -> 24 waves/CU TLP.
// EPI 0: Cb[m*512+n]      = bf16(relu(acc+bias)-hist[m*512+n])
// EPI 1: Cb[m*1024+n]     = bf16((acc+bias)-hist[m*1024+n])
//        Cb[m*1024+512+n] = bf16(relu(acc+bias)-hist[m*1024+512+n])
// ---------------------------------------------------------------------------
template<int EPI>
__global__ __launch_bounds__(512, 2)
void gemm_half(const uint4* __restrict__ At, const uint4* __restrict__ Bt,
               const float* __restrict__ bias, const float* __restrict__ hist,
               unsigned short* __restrict__ C, int Mreal, int row_off, int nblk)
{
    __shared__ uint4 lds[3072];   // A [0,1024), B [1024,3072)

    const int tid = threadIdx.x;
    // XCD-aware bijective swizzle (m204 general form)
    const int orig = blockIdx.x;
    const int xcd = orig & 7, q = nblk >> 3, rr = nblk & 7;
    const int lid = (xcd < rr ? xcd * (q + 1) : rr * (q + 1) + (xcd - rr) * q) + (orig >> 3);
    const int bm = lid >> 1, bnh = lid & 1;   // bnh = which 256-col half

    const int w = tid >> 6, lane = tid & 63;
    const int wm = w >> 2, wn = w & 3;        // wave grid 2M x 4N
    const int lg = lane >> 4, lr = lane & 15;
    const int sw = lr & 7;

    f32x4 acc[4][4];
#pragma unroll
    for (int i = 0; i < 4; ++i)
#pragma unroll
        for (int j = 0; j < 4; ++j) acc[i][j] = {0.f, 0.f, 0.f, 0.f};

    for (int kt = 0; kt < 8; ++kt) {
        if (kt) __syncthreads();          // all waves done reading LDS
        // ---- stage A tile (16 KB) via DMA from pre-tiled planes ----
        {
            const uint4* Ablk = At + ((size_t)bm * 8 + kt) * 1024;
            GLOAD_LDS(Ablk + tid, &lds[tid]);
            GLOAD_LDS(Ablk + 512 + tid, &lds[512 + tid]);
        }
        // ---- stage B tile (256 rows x 64 k = 32 KB, L2-hot) ----
#pragma unroll
        for (int j = 0; j < 4; ++j) {
            const int sl = w * 256 + j * 64 + lane;     // 0..2047
            const int sub = sl >> 10;                   // which 128-row subtile
            const int off = sl & 1023;
            GLOAD_LDS(Bt + ((size_t)(2 * bnh + sub) * 8 + kt) * 1024 + off,
                      &lds[1024 + sl]);
        }
        __syncthreads();                  // compiler drains vmcnt+lgkm here

        bf16x8 a[4][2], b[4][2];
#pragma unroll
        for (int mi = 0; mi < 4; ++mi) {
            const uint4* rp = &lds[(wm * 64 + mi * 16 + lr) * 8];
            a[mi][0] = *(const bf16x8*)&rp[lg ^ sw];
            a[mi][1] = *(const bf16x8*)&rp[(4 + lg) ^ sw];
        }
#pragma unroll
        for (int ni = 0; ni < 4; ++ni) {
            const uint4* rp = &lds[1024 + (wn * 64 + ni * 16 + lr) * 8];
            b[ni][0] = *(const bf16x8*)&rp[lg ^ sw];
            b[ni][1] = *(const bf16x8*)&rp[(4 + lg) ^ sw];
        }
#pragma unroll
        for (int kk = 0; kk < 2; ++kk)
#pragma unroll
            for (int mi = 0; mi < 4; ++mi)
#pragma unroll
                for (int ni = 0; ni < 4; ++ni)
                    acc[mi][ni] = __builtin_amdgcn_mfma_f32_16x16x32_bf16(
                        a[mi][kk], b[ni][kk], acc[mi][ni], 0, 0, 0);
    }

    // epilogue: C/D layout col=lane&15, row=(lane>>4)*4+reg  (m89)
#pragma unroll
    for (int mi = 0; mi < 4; ++mi)
#pragma unroll
        for (int ni = 0; ni < 4; ++ni) {
            const int col = bnh * 256 + wn * 64 + ni * 16 + lr;
            const float bv = bias[col];
#pragma unroll
            for (int r = 0; r < 4; ++r) {
                const int m = row_off + bm * 128 + wm * 64 + mi * 16 + lg * 4 + r;
                if (m < Mreal) {
                    const float v = acc[mi][ni][r] + bv;
                    if (EPI == 0) {
                        C[(size_t)m * 512 + col] = to_bf(fmaxf(v, 0.f) - hist[(size_t)m * 512 + col]);
                    } else {
                        C[(size_t)m * 1024 + col]       = to_bf(v - hist[(size_t)m * 1024 + col]);
                        C[(size_t)m * 1024 + 512 + col] = to_bf(fmaxf(v, 0.f) - hist[(size_t)m * 1024 + 512 + col]);
                    }
                }
            }
        }
}

// ---------------------------------------------------------------------------
// Small GEMM: out[M,64] = A[M,1024] @ B[64,1024]^T + bias  (fp32 classifier)
// ---------------------------------------------------------------------------
__global__ __launch_bounds__(256)
void gemm64(const float* __restrict__ A, const float* __restrict__ B,
            const float* __restrict__ bias, float* __restrict__ C, int M)
{
    const int K = 1024;
    __shared__ float As[32][68];
    __shared__ float Bs[32][68];
    const int tid = threadIdx.x;
    const int tx = tid & 15, ty = tid >> 4;
    const int lrow = tid >> 3;
    const int lk   = (tid & 7) * 4;
    const int bm = blockIdx.x;

    float acc[4][4];
#pragma unroll
    for (int i = 0; i < 4; ++i)
#pragma unroll
        for (int j = 0; j < 4; ++j) acc[i][j] = 0.f;

    int ar0 = bm * 64 + lrow;      if (ar0 > M - 1) ar0 = M - 1;
    int ar1 = bm * 64 + 32 + lrow; if (ar1 > M - 1) ar1 = M - 1;

    for (int kt = 0; kt < K; kt += 32) {
        float4 a0 = *(const float4*)(A + (size_t)ar0 * K + kt + lk);
        float4 a1 = *(const float4*)(A + (size_t)ar1 * K + kt + lk);
        float4 b0 = *(const float4*)(B + (size_t)lrow * K + kt + lk);
        float4 b1 = *(const float4*)(B + (size_t)(32 + lrow) * K + kt + lk);
        __syncthreads();
        As[lk+0][lrow]    = a0.x; As[lk+1][lrow]    = a0.y; As[lk+2][lrow]    = a0.z; As[lk+3][lrow]    = a0.w;
        As[lk+0][lrow+32] = a1.x; As[lk+1][lrow+32] = a1.y; As[lk+2][lrow+32] = a1.z; As[lk+3][lrow+32] = a1.w;
        Bs[lk+0][lrow]    = b0.x; Bs[lk+1][lrow]    = b0.y; Bs[lk+2][lrow]    = b0.z; Bs[lk+3][lrow]    = b0.w;
        Bs[lk+0][lrow+32] = b1.x; Bs[lk+1][lrow+32] = b1.y; Bs[lk+2][lrow+32] = b1.z; Bs[lk+3][lrow+32] = b1.w;
        __syncthreads();
#pragma unroll
        for (int kk = 0; kk < 32; ++kk) {
            float4 av = *(const float4*)&As[kk][ty * 4];
            float4 bv = *(const float4*)&Bs[kk][tx * 4];
            float aa[4] = {av.x, av.y, av.z, av.w};
            float bb[4] = {bv.x, bv.y, bv.z, bv.w};
#pragma unroll
            for (int i = 0; i < 4; ++i)
#pragma unroll
                for (int j = 0; j < 4; ++j)
                    acc[i][j] += aa[i] * bb[j];
        }
    }

    const float4 bv = *(const float4*)&bias[tx * 4];
#pragma unroll
    for (int i = 0; i < 4; ++i) {
        const int m = bm * 64 + ty * 4 + i;
        if (m >= M) continue;
        float4 o;
        o.x = acc[i][0] + bv.x; o.y = acc[i][1] + bv.y;
        o.z = acc[i][2] + bv.z; o.w = acc[i][3] + bv.w;
        *(float4*)&C[(size_t)m * 64 + tx * 4] = o;
    }
}

// ---------------------------------------------------------------------------
// CSR build: degree count -> exclusive scan -> edge scatter
// ---------------------------------------------------------------------------
__global__ void count_deg(const int* __restrict__ dst, int* __restrict__ deg, int E)
{
    int e = blockIdx.x * blockDim.x + threadIdx.x;
    if (e < E) atomicAdd(&deg[dst[e]], 1);
}

__global__ __launch_bounds__(1024)
void exscan(const int* __restrict__ deg, int* __restrict__ off, int* __restrict__ cur, int n)
{
    __shared__ int wsum[16];
    __shared__ int carry;
    const int tid = threadIdx.x, lane = tid & 63, w = tid >> 6;
    if (tid == 0) carry = 0;
    __syncthreads();
    for (int base = 0; base < n; base += 1024) {
        const int i = base + tid;
        const int v = (i < n) ? deg[i] : 0;
        int x = v;
#pragma unroll
        for (int d = 1; d < 64; d <<= 1) {
            int y = __shfl_up(x, d, 64);
            if (lane >= d) x += y;
        }
        if (lane == 63) wsum[w] = x;
        __syncthreads();
        int wo = 0, tot = 0;
#pragma unroll
        for (int k = 0; k < 16; ++k) { int s = wsum[k]; tot += s; if (k < w) wo += s; }
        const int excl = carry + wo + x - v;
        if (i < n) { off[i] = excl; cur[i] = excl; }
        __syncthreads();
        if (tid == 0) carry += tot;
        __syncthreads();
    }
    if (tid == 0) off[n] = carry;
}

__global__ void scatter_edges(const int* __restrict__ src, const int* __restrict__ dst,
                              int* __restrict__ cur, int* __restrict__ eidx, int E)
{
    int e = blockIdx.x * blockDim.x + threadIdx.x;
    if (e < E) {
        int p = atomicAdd(&cur[dst[e]], 1);
        eidx[p] = src[e];
    }
}

// ---------------------------------------------------------------------------
// Segment mean over bf16 h (D=512) + fp32 residual add; writes bf16 tiled
// planes (GEMM2's A). One wave per dst row; lane owns k = lane*8..lane*8+7.
// ---------------------------------------------------------------------------
__global__ __launch_bounds__(256)
void seg_mean_split(const unsigned short* __restrict__ h, const int* __restrict__ off,
                    const int* __restrict__ eidx, const float* __restrict__ addin,
                    uint4* __restrict__ out, int n_dst, int n_pad)
{
    const int wid = blockIdx.x * 4 + (threadIdx.x >> 6);
    const int lane = threadIdx.x & 63;
    if (wid >= n_pad) return;
    uint4 v = {0u, 0u, 0u, 0u};
    if (wid < n_dst) {
        const int e0 = off[wid], e1 = off[wid + 1];
        float s[8];
#pragma unroll
        for (int i = 0; i < 8; ++i) s[i] = 0.f;
        for (int e = e0; e < e1; ++e) {
            const uint4 vv = *((const uint4*)(h + (size_t)eidx[e] * 512) + lane);
            const uint u[4] = {vv.x, vv.y, vv.z, vv.w};
#pragma unroll
            for (int i = 0; i < 4; ++i) {
                s[2 * i]     += __uint_as_float(u[i] << 16);
                s[2 * i + 1] += __uint_as_float(u[i] & 0xFFFF0000u);
            }
        }
        const float sc = 1.0f / (float)((e1 - e0) > 0 ? (e1 - e0) : 1);
        const float* ad = addin + (size_t)wid * 512 + lane * 8;
        float4 d0 = *(const float4*)ad;
        float4 d1 = *(const float4*)(ad + 4);
        v.x = pk_bf(s[0] * sc + d0.x, s[1] * sc + d0.y);
        v.y = pk_bf(s[2] * sc + d0.z, s[3] * sc + d0.w);
        v.z = pk_bf(s[4] * sc + d1.x, s[5] * sc + d1.y);
        v.w = pk_bf(s[6] * sc + d1.z, s[7] * sc + d1.w);
    }
    // tiled layout: [mt*8 + kt8][r*8 + (o ^ (r&7))], kt8 = lane>>3, o = lane&7
    const int mt = wid >> 7, r = wid & 127;
    const int kt8 = lane >> 3, o = lane & 7;
    out[((size_t)(mt * 8 + kt8)) * 1024 + r * 8 + (o ^ (r & 7))] = v;
}

// ---------------------------------------------------------------------------
// Segment mean over bf16 h (D=1024) + fp32 residual add -> fp32 out (agg1)
// ---------------------------------------------------------------------------
__global__ __launch_bounds__(256)
void seg_mean_add4(const unsigned short* __restrict__ h, const int* __restrict__ off,
                   const int* __restrict__ eidx, const float* __restrict__ addin,
                   float* __restrict__ out, int n_dst)
{
    const int wid = blockIdx.x * 4 + (threadIdx.x >> 6);
    const int lane = threadIdx.x & 63;
    if (wid >= n_dst) return;
    const int e0 = off[wid], e1 = off[wid + 1];
    float s[16];
#pragma unroll
    for (int i = 0; i < 16; ++i) s[i] = 0.f;
    for (int e = e0; e < e1; ++e) {
        const uint4* row = (const uint4*)(h + (size_t)eidx[e] * 1024);
#pragma unroll
        for (int half = 0; half < 2; ++half) {
            const uint4 v = row[lane + 64 * half];
            const uint u[4] = {v.x, v.y, v.z, v.w};
#pragma unroll
            for (int i = 0; i < 4; ++i) {
                s[8 * half + 2 * i]     += __uint_as_float(u[i] << 16);
                s[8 * half + 2 * i + 1] += __uint_as_float(u[i] & 0xFFFF0000u);
            }
        }
    }
    const float sc = 1.0f / (float)((e1 - e0) > 0 ? (e1 - e0) : 1);
#pragma unroll
    for (int half = 0; half < 2; ++half) {
        const float* ad = addin + (size_t)wid * 1024 + half * 512 + lane * 8;
        float* o = out + (size_t)wid * 1024 + half * 512 + lane * 8;
        float4 d0 = *(const float4*)ad;
        float4 d1 = *(const float4*)(ad + 4);
        float4 r0, r1;
        r0.x = s[8*half+0] * sc + d0.x; r0.y = s[8*half+1] * sc + d0.y;
        r0.z = s[8*half+2] * sc + d0.z; r0.w = s[8*half+3] * sc + d0.w;
        r1.x = s[8*half+4] * sc + d1.x; r1.y = s[8*half+5] * sc + d1.y;
        r1.z = s[8*half+6] * sc + d1.z; r1.w = s[8*half+7] * sc + d1.w;
        *(float4*)o = r0;
        *(float4*)(o + 4) = r1;
    }
}

// ---------------------------------------------------------------------------
extern "C" void kernel_launch(void* const* d_in, const int* in_sizes, int n_in,
                              void* d_out, int out_size, void* d_ws, size_t ws_size,
                              hipStream_t stream)
{
    const float* feats   = (const float*)d_in[0];
    const float* h0_hist = (const float*)d_in[1];
    const float* agg_h0  = (const float*)d_in[2];
    const float* h1_hist = (const float*)d_in[3];
    const float* agg_h1  = (const float*)d_in[4];
    const float* W0 = (const float*)d_in[5];
    const float* b0 = (const float*)d_in[6];
    const float* W1 = (const float*)d_in[7];
    const float* b1 = (const float*)d_in[8];
    const float* W2 = (const float*)d_in[9];
    const float* b2 = (const float*)d_in[10];
    const int* src0 = (const int*)d_in[11];
    const int* dst0 = (const int*)d_in[12];
    const int* src1 = (const int*)d_in[13];
    const int* dst1 = (const int*)d_in[14];

    const int MT1 = 782;                       // ceil(100000/128)
    const int MT2 = 196;                       // ceil(25000/128)
    const size_t TILEB = 8 * 1024 * 16;        // 128 KiB per M-tile (8 kt x 16KB)

    const size_t h0B   = ((size_t)N0c * 512 * 2 + 255) & ~(size_t)255;   // bf16 h0 (h1cat overlays)
    const size_t a2B   = (size_t)MT2 * TILEB;                            // 25.7 MB
    const size_t agg1B = (size_t)N2c * 1024 * 4;                         // 20.5 MB
    const size_t wsB   = 4 * 8 * 1024 * 16;                              // 512 KB per weight plane
    const size_t intB  = ((size_t)(N1c + (N1c + 1) + N1c + E0c + N2c + (N2c + 1) + N2c + E1c) * 4 + 255) & ~(size_t)255;
    const size_t FIXED = h0B + a2B + agg1B + 2 * wsB + intB;             // ~152 MB

    size_t avail = (ws_size > FIXED) ? (ws_size - FIXED) : 0;
    int ct = (int)(avail / TILEB);
    if (ct < 8) ct = 8;
    if (ct > MT1) ct = MT1;
    const int nchunks = (MT1 + ct - 1) / ct;

    char* ws = (char*)d_ws;
    uint4* Achunk = (uint4*)ws;                              ws += (size_t)ct * TILEB;
    unsigned short* h0 = (unsigned short*)ws;
    unsigned short* h1cat = h0;                              ws += h0B;
    uint4* A2s    = (uint4*)ws;                              ws += a2B;
    float* agg1   = (float*)ws;                              ws += agg1B;
    uint4* Ws0    = (uint4*)ws;                              ws += wsB;
    uint4* Ws1    = (uint4*)ws;                              ws += wsB;
    int* deg0  = (int*)ws;  ws += sizeof(int) * N1c;
    int* off0  = (int*)ws;  ws += sizeof(int) * (N1c + 1);
    int* cur0  = (int*)ws;  ws += sizeof(int) * N1c;
    int* eidx0 = (int*)ws;  ws += sizeof(int) * E0c;
    int* deg1  = (int*)ws;  ws += sizeof(int) * N2c;
    int* off1  = (int*)ws;  ws += sizeof(int) * (N2c + 1);
    int* cur1  = (int*)ws;  ws += sizeof(int) * N2c;
    int* eidx1 = (int*)ws;

    hipMemsetAsync(deg0, 0, sizeof(int) * N1c, stream);
    hipMemsetAsync(deg1, 0, sizeof(int) * N2c, stream);

    // weight planes + CSR level 0 (independent of GEMM1)
    presplit_bf<<<4 * 32, 256, 0, stream>>>(W0, Ws0, 512, 0, 4);
    presplit_bf<<<4 * 32, 256, 0, stream>>>(W1, Ws1, 512, 0, 4);
    count_deg<<<(E0c + 255) / 256, 256, 0, stream>>>(dst0, deg0, E0c);
    exscan<<<1, 1024, 0, stream>>>(deg0, off0, cur0, N1c);
    scatter_edges<<<(E0c + 255) / 256, 256, 0, stream>>>(src0, dst0, cur0, eidx0, E0c);

    // layer 0: h0 = bf16(relu(feats @ W0^T + b0) - h0_hist)   (chunked)
    for (int c = 0; c < nchunks; ++c) {
        const int t0 = c * ct;
        const int nt = (MT1 - t0 < ct) ? (MT1 - t0) : ct;
        presplit_bf<<<nt * 32, 256, 0, stream>>>(feats, Achunk, N0c, t0, nt);
        const int nblk = nt * 2;
        gemm_half<0><<<nblk, 512, 0, stream>>>(Achunk, Ws0, b0, h0_hist, h0, N0c, t0 * 128, nblk);
    }

    // agg0 = segment_mean(h0) + agg_h0, written as bf16 tiled planes
    seg_mean_split<<<(MT2 * 128) / 4, 256, 0, stream>>>(h0, off0, eidx0, agg_h0, A2s, N1c, MT2 * 128);

    // CSR level 1
    count_deg<<<(E1c + 255) / 256, 256, 0, stream>>>(dst1, deg1, E1c);
    exscan<<<1, 1024, 0, stream>>>(deg1, off1, cur1, N2c);
    scatter_edges<<<(E1c + 255) / 256, 256, 0, stream>>>(src1, dst1, cur1, eidx1, E1c);

    // layer 1: h1cat = bf16([h1 | relu(h1)] - h1_hist), h1 = agg0 @ W1^T + b1
    gemm_half<1><<<MT2 * 2, 512, 0, stream>>>(A2s, Ws1, b1, h1_hist, h1cat, N1c, 0, MT2 * 2);

    // agg1 = segment_mean(h1cat) + agg_h1  (fp32)
    seg_mean_add4<<<(N2c + 3) / 4, 256, 0, stream>>>(h1cat, off1, eidx1, agg_h1, agg1, N2c);

    // classifier: out = agg1 @ W2^T + b2
    gemm64<<<(N2c + 63) / 64, 256, 0, stream>>>(agg1, W2, b2, (float*)d_out, N2c);
}